// Round 3
// baseline (459.167 us; speedup 1.0000x reference)
//
#include <hip/hip_runtime.h>
#include <math.h>

#define NN 100000
#define NE 1600000
#define F_IN 128
#define HEADS 4
#define HC 128
#define NEG_SLOPE 0.2f
#define NBKT 1563   // buckets of 64 dst nodes: (NN+63)/64
#define BCAP 1280   // bucket capacity (mean 1024, sigma 32 -> +8 sigma)
#define LDK 136     // padded LDS row (bf16): 128 + 8 -> 2-way bank alias (free)
#define NSTRIP 6250 // NN/16

typedef __attribute__((ext_vector_type(8))) short bf16x8;
typedef __attribute__((ext_vector_type(4))) float f32x4;
typedef __attribute__((ext_vector_type(2))) float f32x2;

static __device__ __forceinline__ short f2bf_rne(float f) {
    unsigned u = __float_as_uint(f);
    unsigned r = (u + 0x7FFFu + ((u >> 16) & 1u)) >> 16;
    return (short)r;
}
static __device__ __forceinline__ float bf2f(short s) {
    return __uint_as_float(((unsigned)(unsigned short)s) << 16);
}
// 2x f32 -> packed bf16 (RNE), one instruction
static __device__ __forceinline__ unsigned cvt_pk_bf16(float a, float b) {
    unsigned r;
    asm("v_cvt_pk_bf16_f32 %0, %1, %2" : "=v"(r) : "v"(a), "v"(b));
    return r;
}

// packed fp32 math (CDNA: full-rate V_PK_*_F32)
static __device__ __forceinline__ void pk_fma(f32x2& d, f32x2 a, f32x2 b) {
    asm("v_pk_fma_f32 %0, %1, %2, %0 op_sel:[0,0,0] op_sel_hi:[1,1,1]"
        : "+v"(d) : "v"(a), "v"(b));
}
static __device__ __forceinline__ void pk_add(f32x2& d, f32x2 a) {
    asm("v_pk_add_f32 %0, %1, %0 op_sel:[0,0] op_sel_hi:[1,1]"
        : "+v"(d) : "v"(a));
}
static __device__ __forceinline__ f32x2 mkpair(float a, float b) {
    f32x2 r; r.x = a; r.y = b; return r;
}

// ---------------------------------------------------------------------------
// Kernel 1: W prep (transpose + bf16 hi/lo split) + int64/int32 detect (blk 0).
__global__ __launch_bounds__(256) void prep_kernel(
        const float* __restrict__ W, short* __restrict__ wt_hi, short* __restrict__ wt_lo,
        const int* __restrict__ ei, int* __restrict__ flag) {
    if (blockIdx.x == 0 && threadIdx.x < 64) {
        int l = threadIdx.x;
        int v = ei[2 * l + 1];
        for (int off = 1; off < 64; off <<= 1) v |= __shfl_xor(v, off);
        if (l == 0) *flag = (v == 0) ? 1 : 0;   // 1 => int64 layout
    }
    int i = blockIdx.x * 256 + threadIdx.x;
    if (i >= F_IN * HC) return;
    int k = i >> 7, n = i & 127;
    float f = W[k * HC + n];
    short hb = f2bf_rne(f);
    wt_hi[n * F_IN + k] = hb;
    wt_lo[n * F_IN + k] = f2bf_rne(f - bf2f(hb));
}

// ---------------------------------------------------------------------------
// Kernel 2: edge scatter, direct per-edge global atomic (no LDS, no local
// histogram -- 1024 atomics/address over 1563 addresses pipeline fine, and
// this removes the 12M LDS-bank-conflict cycles the two-phase version paid).
// 1563 blocks x 256 threads x 4 edges -> ~24 waves/CU for latency hiding.
__global__ __launch_bounds__(256) void scatter_kernel(
        const int* __restrict__ ei, const int* __restrict__ flag,
        int* __restrict__ bcur, unsigned* __restrict__ pairs) {
    int t = threadIdx.x;
    int is64 = *flag;
    int base = blockIdx.x * 1024;
#pragma unroll
    for (int it = 0; it < 4; ++it) {
        int e = base + it * 256 + t;
        if (e < NE) {
            int src = is64 ? ei[2 * e] : ei[e];
            int dst = is64 ? ei[2 * NE + 2 * e] : ei[NE + e];
            int b = dst >> 6;
            int r = atomicAdd(&bcur[b], 1);
            pairs[(size_t)b * BCAP + r] = (unsigned)src | ((unsigned)(dst & 63) << 17);
        }
    }
}

// ---------------------------------------------------------------------------
// Kernel 3: h = x @ W via split-bf16 MFMA. 512-thread blocks (8 strips),
// same 34.8 KB LDS -> 4 blocks x 8 waves = 32 waves/CU (100% occupancy).
// Conversions via v_cvt_pk_bf16_f32 (2 values/instruction).
__global__ __launch_bounds__(512) void mfma_gemm_kernel(
        const float* __restrict__ x, const short* __restrict__ wt_hi,
        const short* __restrict__ wt_lo, const float* __restrict__ att_src,
        const float* __restrict__ att_dst, unsigned short* __restrict__ h_bf,
        float* __restrict__ a_src, float* __restrict__ a_dst) {
    __shared__ short lw_hi[64 * LDK];   // 17 KB
    __shared__ short lw_lo[64 * LDK];   // 17 KB
    int t = threadIdx.x;
    int blk = blockIdx.x;

    // stage W cols 0-63
    for (int c = t; c < 1024; c += 512) {
        int n = c >> 4;
        int kk = (c & 15) * 8;
        *(bf16x8*)(lw_hi + n * LDK + kk) = *(const bf16x8*)(wt_hi + n * F_IN + kk);
        *(bf16x8*)(lw_lo + n * LDK + kk) = *(const bf16x8*)(wt_lo + n * F_IN + kk);
    }
    __syncthreads();

    int strip = blk * 8 + (t >> 6);
    int valid = strip < NSTRIP;
    int sclamp = valid ? strip : NSTRIP - 1;   // clamp: keep all waves alive for barriers
    int lane = t & 63;
    int l15 = lane & 15;
    int q = lane >> 4;

    f32x4 acc[8];
#pragma unroll
    for (int nt = 0; nt < 8; ++nt) acc[nt] = (f32x4){0.f, 0.f, 0.f, 0.f};

    union BU { bf16x8 v; unsigned u[4]; };
    BU ah[4], al[4];
    const float* xp = x + (size_t)(sclamp * 16 + l15) * F_IN + q * 8;

    // phase 1: load+convert x fragments (kept in regs), MFMA cols 0-63
#pragma unroll
    for (int ki = 0; ki < 4; ++ki) {
        float4 v0 = *(const float4*)(xp + ki * 32);
        float4 v1 = *(const float4*)(xp + ki * 32 + 4);
        float vv[8] = {v0.x, v0.y, v0.z, v0.w, v1.x, v1.y, v1.z, v1.w};
#pragma unroll
        for (int j = 0; j < 4; ++j) {
            float f0 = vv[2 * j], f1 = vv[2 * j + 1];
            unsigned hp = cvt_pk_bf16(f0, f1);
            ah[ki].u[j] = hp;
            float r0 = f0 - __uint_as_float(hp << 16);
            float r1 = f1 - __uint_as_float(hp & 0xFFFF0000u);
            al[ki].u[j] = cvt_pk_bf16(r0, r1);
        }
        int koff = ki * 32 + q * 8;
#pragma unroll
        for (int nt = 0; nt < 4; ++nt) {
            int lidx = (nt * 16 + l15) * LDK + koff;
            bf16x8 b_hi = *(const bf16x8*)(lw_hi + lidx);
            bf16x8 b_lo = *(const bf16x8*)(lw_lo + lidx);
            acc[nt] = __builtin_amdgcn_mfma_f32_16x16x32_bf16(ah[ki].v, b_hi, acc[nt], 0, 0, 0);
            acc[nt] = __builtin_amdgcn_mfma_f32_16x16x32_bf16(al[ki].v, b_hi, acc[nt], 0, 0, 0);
            acc[nt] = __builtin_amdgcn_mfma_f32_16x16x32_bf16(ah[ki].v, b_lo, acc[nt], 0, 0, 0);
        }
    }

    // re-stage W cols 64-127 (W is L2-resident; x is not -- this trade wins)
    __syncthreads();
    for (int c = t; c < 1024; c += 512) {
        int n = c >> 4;
        int kk = (c & 15) * 8;
        *(bf16x8*)(lw_hi + n * LDK + kk) = *(const bf16x8*)(wt_hi + (64 + n) * F_IN + kk);
        *(bf16x8*)(lw_lo + n * LDK + kk) = *(const bf16x8*)(wt_lo + (64 + n) * F_IN + kk);
    }
    __syncthreads();

    // phase 2: MFMA cols 64-127 from the registered A-fragments
#pragma unroll
    for (int ki = 0; ki < 4; ++ki) {
        int koff = ki * 32 + q * 8;
#pragma unroll
        for (int nt = 0; nt < 4; ++nt) {
            int lidx = (nt * 16 + l15) * LDK + koff;
            bf16x8 b_hi = *(const bf16x8*)(lw_hi + lidx);
            bf16x8 b_lo = *(const bf16x8*)(lw_lo + lidx);
            acc[4 + nt] = __builtin_amdgcn_mfma_f32_16x16x32_bf16(ah[ki].v, b_hi, acc[4 + nt], 0, 0, 0);
            acc[4 + nt] = __builtin_amdgcn_mfma_f32_16x16x32_bf16(al[ki].v, b_hi, acc[4 + nt], 0, 0, 0);
            acc[4 + nt] = __builtin_amdgcn_mfma_f32_16x16x32_bf16(ah[ki].v, b_lo, acc[4 + nt], 0, 0, 0);
        }
    }

    if (!valid) return;

    int orow = strip * 16 + q * 4;
#pragma unroll
    for (int nt = 0; nt < 8; ++nt)
#pragma unroll
        for (int r = 0; r < 4; ++r)
            h_bf[(size_t)(orow + r) * HC + nt * 16 + l15] =
                (unsigned short)f2bf_rne(acc[nt][r]);

    // attention dots: all 4 heads; head hd uses acc[2hd], acc[2hd+1]
#pragma unroll
    for (int hd = 0; hd < 4; ++hd) {
        float as0 = att_src[hd * 32 + l15];
        float as1 = att_src[hd * 32 + 16 + l15];
        float ad0 = att_dst[hd * 32 + l15];
        float ad1 = att_dst[hd * 32 + 16 + l15];
#pragma unroll
        for (int r = 0; r < 4; ++r) {
            float ps = acc[2 * hd][r] * as0 + acc[2 * hd + 1][r] * as1;
            float pd = acc[2 * hd][r] * ad0 + acc[2 * hd + 1][r] * ad1;
#pragma unroll
            for (int off = 1; off < 16; off <<= 1) {
                ps += __shfl_xor(ps, off);
                pd += __shfl_xor(pd, off);
            }
            if (l15 == 0) {
                int row = orow + r;
                a_src[row * 4 + hd] = ps;
                a_dst[row * 4 + hd] = pd;
            }
        }
    }
}

// ---------------------------------------------------------------------------
// Kernel 4: bucket -> CSR + per-edge bf16 weights. 64-node buckets: 1563
// blocks (~6/CU, was 1.5/CU) and 4x shorter per-thread chains.
__global__ __launch_bounds__(256) void bucket_csr_kernel(
        const int* __restrict__ bcur, const unsigned* __restrict__ pairs,
        const float* __restrict__ a_src, const float* __restrict__ a_dst,
        int* __restrict__ deg, int* __restrict__ offsets,
        int* __restrict__ csr_src, unsigned* __restrict__ wal) {
    __shared__ unsigned lpairs[BCAP];   // 5 KB
    __shared__ int sd[256];
    __shared__ int cnt64[64];
    __shared__ int lcur[64];

    int b = blockIdx.x;
    int t = threadIdx.x;

    // bucket base = prefix sum of bcur[0..b)
    int partial = 0;
    for (int i = t; i < b; i += 256) partial += bcur[i];
    sd[t] = partial;
    __syncthreads();
    for (int off = 128; off > 0; off >>= 1) {
        if (t < off) sd[t] += sd[t + off];
        __syncthreads();
    }
    int bktbase = sd[0];
    __syncthreads();

    if (t < 64) cnt64[t] = 0;
    __syncthreads();

    int cnt = bcur[b];
    const unsigned* __restrict__ bp = pairs + (size_t)b * BCAP;
    for (int i = t; i < cnt; i += 256) {
        unsigned w = bp[i];
        lpairs[i] = w;
        atomicAdd(&cnt64[w >> 17], 1);
    }
    __syncthreads();

    // exclusive scan over the 64 per-node counts
    if (t < 64) sd[t] = cnt64[t];
    __syncthreads();
    for (int off = 1; off < 64; off <<= 1) {
        int u = 0;
        if (t < 64 && t >= off) u = sd[t - off];
        __syncthreads();
        if (t < 64) sd[t] += u;
        __syncthreads();
    }
    if (t < 64) {
        int v = cnt64[t];
        int myoff = bktbase + sd[t] - v;
        int node = (b << 6) + t;
        if (node < NN) {
            deg[node] = v;
            offsets[node] = myoff;
        }
        lcur[t] = myoff;
    }
    __syncthreads();

    for (int i = t; i < cnt; i += 256) {
        unsigned w = lpairs[i];
        int src = (int)(w & 0x1FFFFu);
        int dl = (int)(w >> 17);
        float4 as = ((const float4*)a_src)[src];
        float4 ad = ((const float4*)a_dst)[(b << 6) + dl];
        float e0 = as.x + ad.x; e0 = (e0 < 0.f) ? NEG_SLOPE * e0 : e0;
        float e1 = as.y + ad.y; e1 = (e1 < 0.f) ? NEG_SLOPE * e1 : e1;
        float e2 = as.z + ad.z; e2 = (e2 < 0.f) ? NEG_SLOPE * e2 : e2;
        float e3 = as.w + ad.w; e3 = (e3 < 0.f) ? NEG_SLOPE * e3 : e3;
        float w0 = __expf(e0), w1 = __expf(e1), w2 = __expf(e2), w3 = __expf(e3);
        int pos = atomicAdd(&lcur[dl], 1);
        csr_src[pos] = src;
        unsigned lo = (unsigned)(unsigned short)f2bf_rne(w0) |
                      ((unsigned)(unsigned short)f2bf_rne(w1) << 16);
        unsigned hi = (unsigned)(unsigned short)f2bf_rne(w2) |
                      ((unsigned)(unsigned short)f2bf_rne(w3) << 16);
        ((uint2*)wal)[pos] = make_uint2(lo, hi);
    }
}

// ---------------------------------------------------------------------------
// Kernel 5: per-node aggregation (unchanged from R2).
__global__ __launch_bounds__(256) void gat_aggr_kernel(
        const int* __restrict__ offsets, const int* __restrict__ deg,
        const int* __restrict__ csr_src, const unsigned* __restrict__ wal,
        const float* __restrict__ a_src, const float* __restrict__ a_dst,
        const unsigned* __restrict__ h2, const float* __restrict__ bias,
        float* __restrict__ out) {
    int wid = (blockIdx.x * 256 + threadIdx.x) >> 6;
    int dst = __builtin_amdgcn_readfirstlane(wid);
    if (dst >= NN) return;
    int lane = threadIdx.x & 63;
    int hd = lane >> 4;
    unsigned hsel2 = (unsigned)(hd & 2);
    unsigned shamt = (hd & 1) ? 0u : 16u;

    int start = offsets[dst];
    int n = deg[dst];

    f32x2 accx2 = {0.f, 0.f}, accy2 = {0.f, 0.f}, ws2 = {0.f, 0.f};

    int j = 0;
    for (; j + 7 < n; j += 8) {
        int base = start + j;
        int s0 = csr_src[base + 0];
        int s1 = csr_src[base + 1];
        int s2 = csr_src[base + 2];
        int s3 = csr_src[base + 3];
        int s4 = csr_src[base + 4];
        int s5 = csr_src[base + 5];
        int s6 = csr_src[base + 6];
        int s7 = csr_src[base + 7];
        uint2 wv0 = ((const uint2*)wal)[base + 0];
        uint2 wv1 = ((const uint2*)wal)[base + 1];
        uint2 wv2 = ((const uint2*)wal)[base + 2];
        uint2 wv3 = ((const uint2*)wal)[base + 3];
        uint2 wv4 = ((const uint2*)wal)[base + 4];
        uint2 wv5 = ((const uint2*)wal)[base + 5];
        uint2 wv6 = ((const uint2*)wal)[base + 6];
        uint2 wv7 = ((const uint2*)wal)[base + 7];
        unsigned u0 = h2[(size_t)s0 * 64 + lane];
        unsigned u1 = h2[(size_t)s1 * 64 + lane];
        unsigned u2 = h2[(size_t)s2 * 64 + lane];
        unsigned u3 = h2[(size_t)s3 * 64 + lane];
        unsigned u4 = h2[(size_t)s4 * 64 + lane];
        unsigned u5 = h2[(size_t)s5 * 64 + lane];
        unsigned u6 = h2[(size_t)s6 * 64 + lane];
        unsigned u7 = h2[(size_t)s7 * 64 + lane];
#define EDGEPAIR(ua, ub, wva, wvb)                                              \
        {                                                                       \
            unsigned wsa = hsel2 ? wva.y : wva.x;                               \
            unsigned wsb = hsel2 ? wvb.y : wvb.x;                               \
            f32x2 wp = mkpair(__uint_as_float((wsa << shamt) & 0xFFFF0000u),    \
                              __uint_as_float((wsb << shamt) & 0xFFFF0000u));   \
            f32x2 hx = mkpair(__uint_as_float(ua << 16),                        \
                              __uint_as_float(ub << 16));                       \
            f32x2 hy = mkpair(__uint_as_float(ua & 0xFFFF0000u),                \
                              __uint_as_float(ub & 0xFFFF0000u));               \
            pk_add(ws2, wp);                                                    \
            pk_fma(accx2, wp, hx);                                              \
            pk_fma(accy2, wp, hy);                                              \
        }
        EDGEPAIR(u0, u1, wv0, wv1)
        EDGEPAIR(u2, u3, wv2, wv3)
        EDGEPAIR(u4, u5, wv4, wv5)
        EDGEPAIR(u6, u7, wv6, wv7)
    }
    for (; j + 1 < n; j += 2) {
        int base = start + j;
        int s0 = csr_src[base + 0];
        int s1 = csr_src[base + 1];
        uint2 wv0 = ((const uint2*)wal)[base + 0];
        uint2 wv1 = ((const uint2*)wal)[base + 1];
        unsigned u0 = h2[(size_t)s0 * 64 + lane];
        unsigned u1 = h2[(size_t)s1 * 64 + lane];
        EDGEPAIR(u0, u1, wv0, wv1)
    }
#undef EDGEPAIR
    float accx = accx2.x + accx2.y;
    float accy = accy2.x + accy2.y;
    float wsum = ws2.x + ws2.y;
    if (j < n) {
        int base = start + j;
        int s0 = csr_src[base];
        uint2 wv0 = ((const uint2*)wal)[base];
        unsigned u0 = h2[(size_t)s0 * 64 + lane];
        unsigned ws0 = hsel2 ? wv0.y : wv0.x;
        float w0 = __uint_as_float((ws0 << shamt) & 0xFFFF0000u);
        wsum += w0;
        accx += w0 * __uint_as_float(u0 << 16);
        accy += w0 * __uint_as_float(u0 & 0xFFFF0000u);
    }

    float e = a_src[dst * 4 + hd] + a_dst[dst * 4 + hd];
    e = (e < 0.f) ? NEG_SLOPE * e : e;
    float sf = __expf(e);
    float inv = 1.f / (wsum + sf + 1e-16f);

    unsigned us = h2[(size_t)dst * 64 + lane];
    float2 b2 = ((const float2*)bias)[lane];
    float ox = tanhf((accx + sf * __uint_as_float(us << 16)) * inv + b2.x);
    float oy = tanhf((accy + sf * __uint_as_float(us & 0xFFFF0000u)) * inv + b2.y);
    ((float2*)out)[(size_t)dst * 64 + lane] = make_float2(ox, oy);
}

// ---------------------------------------------------------------------------
extern "C" void kernel_launch(void* const* d_in, const int* in_sizes, int n_in,
                              void* d_out, int out_size, void* d_ws, size_t ws_size,
                              hipStream_t stream) {
    const float* x       = (const float*)d_in[0];
    const int*   ei      = (const int*)  d_in[1];
    const float* W       = (const float*)d_in[2];
    const float* att_src = (const float*)d_in[3];
    const float* att_dst = (const float*)d_in[4];
    const float* bias    = (const float*)d_in[5];
    float* out = (float*)d_out;

    unsigned short* h_bf = (unsigned short*)d_ws;            // NN*128 bf16 (25.6 MB)
    float* a_src = (float*)(h_bf + (size_t)NN * HC);         // NN*4
    float* a_dst = a_src + (size_t)NN * HEADS;               // NN*4
    short* wt_hi = (short*)(a_dst + (size_t)NN * HEADS);     // 16384
    short* wt_lo = wt_hi + F_IN * HC;                        // 16384
    int* flag    = (int*)(wt_lo + F_IN * HC);
    int* bcur    = flag + 4;                 // NBKT
    int* deg     = bcur + NBKT + 1;          // NN
    int* offsets = deg + NN;                 // NN
    int* csr_src = offsets + NN;             // NE (6.4 MB)
    unsigned* wal = (unsigned*)(csr_src + NE);               // NE*2 (12.8 MB)
    unsigned* pairs = (unsigned*)(wal + (size_t)NE * 2);     // NBKT*BCAP (8 MB)

    hipMemsetAsync(bcur, 0, NBKT * sizeof(int), stream);

    hipLaunchKernelGGL(prep_kernel, dim3(64), dim3(256), 0, stream,
                       W, wt_hi, wt_lo, ei, flag);

    hipLaunchKernelGGL(scatter_kernel, dim3((NE + 1023) / 1024), dim3(256), 0, stream,
                       ei, flag, bcur, pairs);

    // 782 row-blocks (128 rows each, 8 strips/block, last partial)
    hipLaunchKernelGGL(mfma_gemm_kernel, dim3(782), dim3(512), 0, stream,
                       x, wt_hi, wt_lo, att_src, att_dst, h_bf, a_src, a_dst);

    hipLaunchKernelGGL(bucket_csr_kernel, dim3(NBKT), dim3(256), 0, stream,
                       bcur, pairs, a_src, a_dst, deg, offsets, csr_src, wal);

    hipLaunchKernelGGL(gat_aggr_kernel, dim3(NN * 64 / 256), dim3(256), 0, stream,
                       offsets, deg, csr_src, wal, a_src, a_dst,
                       (const unsigned*)h_bf, bias, out);
}

// Round 5
// 374.797 us; speedup vs baseline: 1.2251x; 1.2251x over previous
//
#include <hip/hip_runtime.h>
#include <math.h>

#define NN 100000
#define NE 1600000
#define F_IN 128
#define HEADS 4
#define HC 128
#define NEG_SLOPE 0.2f
#define LDK 136     // padded LDS row (bf16): 128 + 8 -> 2-way bank alias (free)
#define NSTRIP 6250 // NN/16
#define NBLK 391    // scan blocks: (NN+255)/256

typedef __attribute__((ext_vector_type(8))) short bf16x8;
typedef __attribute__((ext_vector_type(4))) float f32x4;
typedef __attribute__((ext_vector_type(2))) float f32x2;

static __device__ __forceinline__ short f2bf_rne(float f) {
    unsigned u = __float_as_uint(f);
    unsigned r = (u + 0x7FFFu + ((u >> 16) & 1u)) >> 16;
    return (short)r;
}
static __device__ __forceinline__ float bf2f(short s) {
    return __uint_as_float(((unsigned)(unsigned short)s) << 16);
}
// 2x f32 -> packed bf16 (RNE), one instruction
static __device__ __forceinline__ unsigned cvt_pk_bf16(float a, float b) {
    unsigned r;
    asm("v_cvt_pk_bf16_f32 %0, %1, %2" : "=v"(r) : "v"(a), "v"(b));
    return r;
}

// packed fp32 math (CDNA: full-rate V_PK_*_F32)
static __device__ __forceinline__ void pk_fma(f32x2& d, f32x2 a, f32x2 b) {
    asm("v_pk_fma_f32 %0, %1, %2, %0 op_sel:[0,0,0] op_sel_hi:[1,1,1]"
        : "+v"(d) : "v"(a), "v"(b));
}
static __device__ __forceinline__ void pk_add(f32x2& d, f32x2 a) {
    asm("v_pk_add_f32 %0, %1, %0 op_sel:[0,0] op_sel_hi:[1,1]"
        : "+v"(d) : "v"(a));
}
static __device__ __forceinline__ f32x2 mkpair(float a, float b) {
    f32x2 r; r.x = a; r.y = b; return r;
}

// ---------------------------------------------------------------------------
// Kernel 1: W prep (transpose + bf16 hi/lo split) + int64/int32 detect (blk 0).
__global__ __launch_bounds__(256) void prep_kernel(
        const float* __restrict__ W, short* __restrict__ wt_hi, short* __restrict__ wt_lo,
        const int* __restrict__ ei, int* __restrict__ flag) {
    if (blockIdx.x == 0 && threadIdx.x < 64) {
        int l = threadIdx.x;
        int v = ei[2 * l + 1];
        for (int off = 1; off < 64; off <<= 1) v |= __shfl_xor(v, off);
        if (l == 0) *flag = (v == 0) ? 1 : 0;   // 1 => int64 layout
    }
    int i = blockIdx.x * 256 + threadIdx.x;
    if (i >= F_IN * HC) return;
    int k = i >> 7, n = i & 127;
    float f = W[k * HC + n];
    short hb = f2bf_rne(f);
    wt_hi[n * F_IN + k] = hb;
    wt_lo[n * F_IN + k] = f2bf_rne(f - bf2f(hb));
}

// ---------------------------------------------------------------------------
// Kernel 2: degree histogram + rank capture. ~16 atomics/address (fine; R3
// showed ~1000/address is the catastrophe). tmp[e] = rank only (no packing).
__global__ __launch_bounds__(256) void hist_kernel(
        const int* __restrict__ ei, const int* __restrict__ flag,
        int* __restrict__ deg, int* __restrict__ tmp) {
    int t = threadIdx.x;
    int is64 = *flag;
    int base = blockIdx.x * 2048;
#pragma unroll
    for (int it = 0; it < 8; ++it) {
        int e = base + it * 256 + t;
        if (e < NE) {
            int dst = is64 ? ei[2 * NE + 2 * e] : ei[NE + e];
            tmp[e] = atomicAdd(&deg[dst], 1);
        }
    }
}

// ---------------------------------------------------------------------------
// Kernel 3a: per-256-node-block exclusive scan (block-local) + block totals.
__global__ __launch_bounds__(256) void scan1_kernel(
        const int* __restrict__ deg, int* __restrict__ offsets, int* __restrict__ parts) {
    __shared__ int sd[256];
    int b = blockIdx.x, t = threadIdx.x;
    int node = b * 256 + t;
    int v = (node < NN) ? deg[node] : 0;
    sd[t] = v;
    __syncthreads();
    for (int off = 1; off < 256; off <<= 1) {
        int u = (t >= off) ? sd[t - off] : 0;
        __syncthreads();
        sd[t] += u;
        __syncthreads();
    }
    if (node < NN) offsets[node] = sd[t] - v;
    if (t == 255) parts[b] = sd[255];
}

// Kernel 3b: single-block exclusive scan of the 391 block totals.
__global__ __launch_bounds__(512) void scan2_kernel(int* __restrict__ parts) {
    __shared__ int sd[512];
    int t = threadIdx.x;
    int v = (t < NBLK) ? parts[t] : 0;
    sd[t] = v;
    __syncthreads();
    for (int off = 1; off < 512; off <<= 1) {
        int u = (t >= off) ? sd[t - off] : 0;
        __syncthreads();
        sd[t] += u;
        __syncthreads();
    }
    if (t < NBLK) parts[t] = sd[t] - v;
}

// Kernel 3c: fold block partials into offsets -> offsets[] is the final
// global exclusive prefix sum of deg. Consumers use plain offsets[dst].
__global__ __launch_bounds__(256) void addback_kernel(
        int* __restrict__ offsets, const int* __restrict__ parts) {
    int node = blockIdx.x * 256 + threadIdx.x;
    if (node < NN) offsets[node] += parts[blockIdx.x];
}

// ---------------------------------------------------------------------------
// Kernel 4: h = x @ W via split-bf16 MFMA (R3-passing version, unchanged).
__global__ __launch_bounds__(512) void mfma_gemm_kernel(
        const float* __restrict__ x, const short* __restrict__ wt_hi,
        const short* __restrict__ wt_lo, const float* __restrict__ att_src,
        const float* __restrict__ att_dst, unsigned short* __restrict__ h_bf,
        float* __restrict__ a_src, float* __restrict__ a_dst) {
    __shared__ short lw_hi[64 * LDK];   // 17 KB
    __shared__ short lw_lo[64 * LDK];   // 17 KB
    int t = threadIdx.x;
    int blk = blockIdx.x;

    for (int c = t; c < 1024; c += 512) {
        int n = c >> 4;
        int kk = (c & 15) * 8;
        *(bf16x8*)(lw_hi + n * LDK + kk) = *(const bf16x8*)(wt_hi + n * F_IN + kk);
        *(bf16x8*)(lw_lo + n * LDK + kk) = *(const bf16x8*)(wt_lo + n * F_IN + kk);
    }
    __syncthreads();

    int strip = blk * 8 + (t >> 6);
    int valid = strip < NSTRIP;
    int sclamp = valid ? strip : NSTRIP - 1;
    int lane = t & 63;
    int l15 = lane & 15;
    int q = lane >> 4;

    f32x4 acc[8];
#pragma unroll
    for (int nt = 0; nt < 8; ++nt) acc[nt] = (f32x4){0.f, 0.f, 0.f, 0.f};

    union BU { bf16x8 v; unsigned u[4]; };
    BU ah[4], al[4];
    const float* xp = x + (size_t)(sclamp * 16 + l15) * F_IN + q * 8;

#pragma unroll
    for (int ki = 0; ki < 4; ++ki) {
        float4 v0 = *(const float4*)(xp + ki * 32);
        float4 v1 = *(const float4*)(xp + ki * 32 + 4);
        float vv[8] = {v0.x, v0.y, v0.z, v0.w, v1.x, v1.y, v1.z, v1.w};
#pragma unroll
        for (int j = 0; j < 4; ++j) {
            float f0 = vv[2 * j], f1 = vv[2 * j + 1];
            unsigned hp = cvt_pk_bf16(f0, f1);
            ah[ki].u[j] = hp;
            float r0 = f0 - __uint_as_float(hp << 16);
            float r1 = f1 - __uint_as_float(hp & 0xFFFF0000u);
            al[ki].u[j] = cvt_pk_bf16(r0, r1);
        }
        int koff = ki * 32 + q * 8;
#pragma unroll
        for (int nt = 0; nt < 4; ++nt) {
            int lidx = (nt * 16 + l15) * LDK + koff;
            bf16x8 b_hi = *(const bf16x8*)(lw_hi + lidx);
            bf16x8 b_lo = *(const bf16x8*)(lw_lo + lidx);
            acc[nt] = __builtin_amdgcn_mfma_f32_16x16x32_bf16(ah[ki].v, b_hi, acc[nt], 0, 0, 0);
            acc[nt] = __builtin_amdgcn_mfma_f32_16x16x32_bf16(al[ki].v, b_hi, acc[nt], 0, 0, 0);
            acc[nt] = __builtin_amdgcn_mfma_f32_16x16x32_bf16(ah[ki].v, b_lo, acc[nt], 0, 0, 0);
        }
    }

    __syncthreads();
    for (int c = t; c < 1024; c += 512) {
        int n = c >> 4;
        int kk = (c & 15) * 8;
        *(bf16x8*)(lw_hi + n * LDK + kk) = *(const bf16x8*)(wt_hi + (64 + n) * F_IN + kk);
        *(bf16x8*)(lw_lo + n * LDK + kk) = *(const bf16x8*)(wt_lo + (64 + n) * F_IN + kk);
    }
    __syncthreads();

#pragma unroll
    for (int ki = 0; ki < 4; ++ki) {
        int koff = ki * 32 + q * 8;
#pragma unroll
        for (int nt = 0; nt < 4; ++nt) {
            int lidx = (nt * 16 + l15) * LDK + koff;
            bf16x8 b_hi = *(const bf16x8*)(lw_hi + lidx);
            bf16x8 b_lo = *(const bf16x8*)(lw_lo + lidx);
            acc[4 + nt] = __builtin_amdgcn_mfma_f32_16x16x32_bf16(ah[ki].v, b_hi, acc[4 + nt], 0, 0, 0);
            acc[4 + nt] = __builtin_amdgcn_mfma_f32_16x16x32_bf16(al[ki].v, b_hi, acc[4 + nt], 0, 0, 0);
            acc[4 + nt] = __builtin_amdgcn_mfma_f32_16x16x32_bf16(ah[ki].v, b_lo, acc[4 + nt], 0, 0, 0);
        }
    }

    if (!valid) return;

    int orow = strip * 16 + q * 4;
#pragma unroll
    for (int nt = 0; nt < 8; ++nt)
#pragma unroll
        for (int r = 0; r < 4; ++r)
            h_bf[(size_t)(orow + r) * HC + nt * 16 + l15] =
                (unsigned short)f2bf_rne(acc[nt][r]);

#pragma unroll
    for (int hd = 0; hd < 4; ++hd) {
        float as0 = att_src[hd * 32 + l15];
        float as1 = att_src[hd * 32 + 16 + l15];
        float ad0 = att_dst[hd * 32 + l15];
        float ad1 = att_dst[hd * 32 + 16 + l15];
#pragma unroll
        for (int r = 0; r < 4; ++r) {
            float ps = acc[2 * hd][r] * as0 + acc[2 * hd + 1][r] * as1;
            float pd = acc[2 * hd][r] * ad0 + acc[2 * hd + 1][r] * ad1;
#pragma unroll
            for (int off = 1; off < 16; off <<= 1) {
                ps += __shfl_xor(ps, off);
                pd += __shfl_xor(pd, off);
            }
            if (l15 == 0) {
                int row = orow + r;
                a_src[row * 4 + hd] = ps;
                a_dst[row * 4 + hd] = pd;
            }
        }
    }
}

// ---------------------------------------------------------------------------
// Kernel 5: atomic-free CSR scatter + per-edge weight computation (the old
// bucket_csr's only real work, without buckets/LDS/atomics). pos = row start
// + the rank captured in hist -- a bijection onto [0,NE).
__global__ __launch_bounds__(256) void scatter_kernel(
        const int* __restrict__ ei, const int* __restrict__ flag,
        const int* __restrict__ offsets, const int* __restrict__ tmp,
        const float* __restrict__ a_src, const float* __restrict__ a_dst,
        int* __restrict__ csr_src, unsigned* __restrict__ wal) {
    int t = threadIdx.x;
    int is64 = *flag;
    int base = blockIdx.x * 2048;
#pragma unroll
    for (int it = 0; it < 8; ++it) {
        int e = base + it * 256 + t;
        if (e < NE) {
            int src = is64 ? ei[2 * e] : ei[e];
            int dst = is64 ? ei[2 * NE + 2 * e] : ei[NE + e];
            int pos = offsets[dst] + tmp[e];
            csr_src[pos] = src;
            float4 as = ((const float4*)a_src)[src];
            float4 ad = ((const float4*)a_dst)[dst];
            float e0 = as.x + ad.x; e0 = (e0 < 0.f) ? NEG_SLOPE * e0 : e0;
            float e1 = as.y + ad.y; e1 = (e1 < 0.f) ? NEG_SLOPE * e1 : e1;
            float e2 = as.z + ad.z; e2 = (e2 < 0.f) ? NEG_SLOPE * e2 : e2;
            float e3 = as.w + ad.w; e3 = (e3 < 0.f) ? NEG_SLOPE * e3 : e3;
            float w0 = __expf(e0), w1 = __expf(e1), w2 = __expf(e2), w3 = __expf(e3);
            unsigned lo = (unsigned)(unsigned short)f2bf_rne(w0) |
                          ((unsigned)(unsigned short)f2bf_rne(w1) << 16);
            unsigned hi = (unsigned)(unsigned short)f2bf_rne(w2) |
                          ((unsigned)(unsigned short)f2bf_rne(w3) << 16);
            ((uint2*)wal)[pos] = make_uint2(lo, hi);
        }
    }
}

// ---------------------------------------------------------------------------
// Kernel 6: per-node aggregation -- R2-measured version verbatim (wal-based
// bf16 weights, in-register wsum, pk math). start = offsets[dst] (final).
__global__ __launch_bounds__(256) void gat_aggr_kernel(
        const int* __restrict__ offsets, const int* __restrict__ deg,
        const int* __restrict__ csr_src, const unsigned* __restrict__ wal,
        const float* __restrict__ a_src, const float* __restrict__ a_dst,
        const unsigned* __restrict__ h2, const float* __restrict__ bias,
        float* __restrict__ out) {
    int wid = (blockIdx.x * 256 + threadIdx.x) >> 6;
    int dst = __builtin_amdgcn_readfirstlane(wid);
    if (dst >= NN) return;
    int lane = threadIdx.x & 63;
    int hd = lane >> 4;
    unsigned hsel2 = (unsigned)(hd & 2);
    unsigned shamt = (hd & 1) ? 0u : 16u;

    int start = offsets[dst];
    int n = deg[dst];

    f32x2 accx2 = {0.f, 0.f}, accy2 = {0.f, 0.f}, ws2 = {0.f, 0.f};

    int j = 0;
    for (; j + 7 < n; j += 8) {
        int base = start + j;
        int s0 = csr_src[base + 0];
        int s1 = csr_src[base + 1];
        int s2 = csr_src[base + 2];
        int s3 = csr_src[base + 3];
        int s4 = csr_src[base + 4];
        int s5 = csr_src[base + 5];
        int s6 = csr_src[base + 6];
        int s7 = csr_src[base + 7];
        uint2 wv0 = ((const uint2*)wal)[base + 0];
        uint2 wv1 = ((const uint2*)wal)[base + 1];
        uint2 wv2 = ((const uint2*)wal)[base + 2];
        uint2 wv3 = ((const uint2*)wal)[base + 3];
        uint2 wv4 = ((const uint2*)wal)[base + 4];
        uint2 wv5 = ((const uint2*)wal)[base + 5];
        uint2 wv6 = ((const uint2*)wal)[base + 6];
        uint2 wv7 = ((const uint2*)wal)[base + 7];
        unsigned u0 = h2[(size_t)s0 * 64 + lane];
        unsigned u1 = h2[(size_t)s1 * 64 + lane];
        unsigned u2 = h2[(size_t)s2 * 64 + lane];
        unsigned u3 = h2[(size_t)s3 * 64 + lane];
        unsigned u4 = h2[(size_t)s4 * 64 + lane];
        unsigned u5 = h2[(size_t)s5 * 64 + lane];
        unsigned u6 = h2[(size_t)s6 * 64 + lane];
        unsigned u7 = h2[(size_t)s7 * 64 + lane];
#define EDGEPAIR(ua, ub, wva, wvb)                                              \
        {                                                                       \
            unsigned wsa = hsel2 ? wva.y : wva.x;                               \
            unsigned wsb = hsel2 ? wvb.y : wvb.x;                               \
            f32x2 wp = mkpair(__uint_as_float((wsa << shamt) & 0xFFFF0000u),    \
                              __uint_as_float((wsb << shamt) & 0xFFFF0000u));   \
            f32x2 hx = mkpair(__uint_as_float(ua << 16),                        \
                              __uint_as_float(ub << 16));                       \
            f32x2 hy = mkpair(__uint_as_float(ua & 0xFFFF0000u),                \
                              __uint_as_float(ub & 0xFFFF0000u));               \
            pk_add(ws2, wp);                                                    \
            pk_fma(accx2, wp, hx);                                              \
            pk_fma(accy2, wp, hy);                                              \
        }
        EDGEPAIR(u0, u1, wv0, wv1)
        EDGEPAIR(u2, u3, wv2, wv3)
        EDGEPAIR(u4, u5, wv4, wv5)
        EDGEPAIR(u6, u7, wv6, wv7)
    }
    for (; j + 1 < n; j += 2) {
        int base = start + j;
        int s0 = csr_src[base + 0];
        int s1 = csr_src[base + 1];
        uint2 wv0 = ((const uint2*)wal)[base + 0];
        uint2 wv1 = ((const uint2*)wal)[base + 1];
        unsigned u0 = h2[(size_t)s0 * 64 + lane];
        unsigned u1 = h2[(size_t)s1 * 64 + lane];
        EDGEPAIR(u0, u1, wv0, wv1)
    }
#undef EDGEPAIR
    float accx = accx2.x + accx2.y;
    float accy = accy2.x + accy2.y;
    float wsum = ws2.x + ws2.y;
    if (j < n) {
        int base = start + j;
        int s0 = csr_src[base];
        uint2 wv0 = ((const uint2*)wal)[base];
        unsigned u0 = h2[(size_t)s0 * 64 + lane];
        unsigned ws0 = hsel2 ? wv0.y : wv0.x;
        float w0 = __uint_as_float((ws0 << shamt) & 0xFFFF0000u);
        wsum += w0;
        accx += w0 * __uint_as_float(u0 << 16);
        accy += w0 * __uint_as_float(u0 & 0xFFFF0000u);
    }

    // self-loop weight + softmax normalization
    float e = a_src[dst * 4 + hd] + a_dst[dst * 4 + hd];
    e = (e < 0.f) ? NEG_SLOPE * e : e;
    float sf = __expf(e);
    float inv = 1.f / (wsum + sf + 1e-16f);

    unsigned us = h2[(size_t)dst * 64 + lane];
    float2 b2 = ((const float2*)bias)[lane];
    float ox = tanhf((accx + sf * __uint_as_float(us << 16)) * inv + b2.x);
    float oy = tanhf((accy + sf * __uint_as_float(us & 0xFFFF0000u)) * inv + b2.y);
    ((float2*)out)[(size_t)dst * 64 + lane] = make_float2(ox, oy);
}

// ---------------------------------------------------------------------------
extern "C" void kernel_launch(void* const* d_in, const int* in_sizes, int n_in,
                              void* d_out, int out_size, void* d_ws, size_t ws_size,
                              hipStream_t stream) {
    const float* x       = (const float*)d_in[0];
    const int*   ei      = (const int*)  d_in[1];
    const float* W       = (const float*)d_in[2];
    const float* att_src = (const float*)d_in[3];
    const float* att_dst = (const float*)d_in[4];
    const float* bias    = (const float*)d_in[5];
    float* out = (float*)d_out;

    unsigned short* h_bf = (unsigned short*)d_ws;            // NN*128 bf16 (25.6 MB)
    float* a_src = (float*)(h_bf + (size_t)NN * HC);         // NN*4 (16B-aligned)
    float* a_dst = a_src + (size_t)NN * HEADS;               // NN*4 (16B-aligned)
    short* wt_hi = (short*)(a_dst + (size_t)NN * HEADS);     // 16384
    short* wt_lo = wt_hi + F_IN * HC;                        // 16384
    int* flag    = (int*)(wt_lo + F_IN * HC);
    int* deg     = flag + 4;                 // NN
    int* offsets = deg + NN;                 // NN
    int* parts   = offsets + NN;             // 512
    int* csr_src = parts + 512;              // NE (6.4 MB)
    unsigned* wal = (unsigned*)(csr_src + NE);               // NE*2 (12.8 MB)
    int* tmp     = (int*)(wal + (size_t)NE * 2);             // NE (6.4 MB)

    hipMemsetAsync(deg, 0, NN * sizeof(int), stream);

    hipLaunchKernelGGL(prep_kernel, dim3(64), dim3(256), 0, stream,
                       W, wt_hi, wt_lo, ei, flag);

    hipLaunchKernelGGL(hist_kernel, dim3((NE + 2047) / 2048), dim3(256), 0, stream,
                       ei, flag, deg, tmp);

    hipLaunchKernelGGL(scan1_kernel, dim3(NBLK), dim3(256), 0, stream,
                       deg, offsets, parts);
    hipLaunchKernelGGL(scan2_kernel, dim3(1), dim3(512), 0, stream, parts);
    hipLaunchKernelGGL(addback_kernel, dim3(NBLK), dim3(256), 0, stream,
                       offsets, parts);

    hipLaunchKernelGGL(mfma_gemm_kernel, dim3(782), dim3(512), 0, stream,
                       x, wt_hi, wt_lo, att_src, att_dst, h_bf, a_src, a_dst);

    hipLaunchKernelGGL(scatter_kernel, dim3((NE + 2047) / 2048), dim3(256), 0, stream,
                       ei, flag, offsets, tmp, a_src, a_dst, csr_src, wal);

    hipLaunchKernelGGL(gat_aggr_kernel, dim3(NN * 64 / 256), dim3(256), 0, stream,
                       offsets, deg, csr_src, wal, a_src, a_dst,
                       (const unsigned*)h_bf, bias, out);
}

// Round 7
// 257.640 us; speedup vs baseline: 1.7822x; 1.4547x over previous
//
#include <hip/hip_runtime.h>
#include <math.h>

#define NN 100000
#define NE 1600000
#define F_IN 128
#define HEADS 4
#define HC 128
#define NEG_SLOPE 0.2f
#define NBKT 1563   // buckets of 64 dst nodes: (NN+63)/64
#define BCAP 1280   // bucket capacity (mean 1024, sd 32 -> +8 sigma; passed R3)
#define LDK 136     // padded LDS row (bf16): 128 + 8 -> 2-way bank alias (free)
#define NSTRIP 6250 // NN/16

typedef __attribute__((ext_vector_type(8))) short bf16x8;
typedef __attribute__((ext_vector_type(4))) float f32x4;
typedef __attribute__((ext_vector_type(2))) float f32x2;

static __device__ __forceinline__ short f2bf_rne(float f) {
    unsigned u = __float_as_uint(f);
    unsigned r = (u + 0x7FFFu + ((u >> 16) & 1u)) >> 16;
    return (short)r;
}
static __device__ __forceinline__ float bf2f(short s) {
    return __uint_as_float(((unsigned)(unsigned short)s) << 16);
}
// 2x f32 -> packed bf16 (RNE), one instruction
static __device__ __forceinline__ unsigned cvt_pk_bf16(float a, float b) {
    unsigned r;
    asm("v_cvt_pk_bf16_f32 %0, %1, %2" : "=v"(r) : "v"(a), "v"(b));
    return r;
}

// packed fp32 math (CDNA: full-rate V_PK_*_F32)
static __device__ __forceinline__ void pk_fma(f32x2& d, f32x2 a, f32x2 b) {
    asm("v_pk_fma_f32 %0, %1, %2, %0 op_sel:[0,0,0] op_sel_hi:[1,1,1]"
        : "+v"(d) : "v"(a), "v"(b));
}
static __device__ __forceinline__ void pk_add(f32x2& d, f32x2 a) {
    asm("v_pk_add_f32 %0, %1, %0 op_sel:[0,0] op_sel_hi:[1,1]"
        : "+v"(d) : "v"(a));
}
static __device__ __forceinline__ f32x2 mkpair(float a, float b) {
    f32x2 r; r.x = a; r.y = b; return r;
}

// ---------------------------------------------------------------------------
// Kernel 1: W prep (transpose + bf16 hi/lo split) + int64/int32 detect (blk 0).
__global__ __launch_bounds__(256) void prep_kernel(
        const float* __restrict__ W, short* __restrict__ wt_hi, short* __restrict__ wt_lo,
        const int* __restrict__ ei, int* __restrict__ flag) {
    if (blockIdx.x == 0 && threadIdx.x < 64) {
        int l = threadIdx.x;
        int v = ei[2 * l + 1];
        for (int off = 1; off < 64; off <<= 1) v |= __shfl_xor(v, off);
        if (l == 0) *flag = (v == 0) ? 1 : 0;   // 1 => int64 layout
    }
    int i = blockIdx.x * 256 + threadIdx.x;
    if (i >= F_IN * HC) return;
    int k = i >> 7, n = i & 127;
    float f = W[k * HC + n];
    short hb = f2bf_rne(f);
    wt_hi[n * F_IN + k] = hb;
    wt_lo[n * F_IN + k] = f2bf_rne(f - bf2f(hb));
}

// ---------------------------------------------------------------------------
// Kernel 2: bucketed multisplit (R0 structure @ 1563 buckets of 64 nodes).
// LDS histogram for ranks; global atomics only per (block,bucket) -- avoids
// the per-dst cacheline-dense atomic pattern that cost hist ~120us in R5.
__global__ __launch_bounds__(256) void bucket_scatter_kernel(
        const int* __restrict__ ei, const int* __restrict__ flag,
        int* __restrict__ bcur, unsigned* __restrict__ pairs) {
    __shared__ int lhist[NBKT];   // 6.25 KB
    __shared__ int gbase[NBKT];   // 6.25 KB
    int t = threadIdx.x;
    for (int i = t; i < NBKT; i += 256) lhist[i] = 0;
    __syncthreads();
    int is64 = *flag;
    int base = blockIdx.x * 4096;

    unsigned wrd[16];
    int meta[16];
#pragma unroll
    for (int it = 0; it < 16; ++it) {
        int e = base + it * 256 + t;
        if (e < NE) {
            int src = is64 ? ei[2 * e] : ei[e];
            int dst = is64 ? ei[2 * NE + 2 * e] : ei[NE + e];
            int b = dst >> 6;
            int r = atomicAdd(&lhist[b], 1);
            wrd[it] = (unsigned)src | ((unsigned)(dst & 63) << 17);
            meta[it] = b | (r << 11);     // b < 2048; r < 4096 in a block
        } else {
            meta[it] = -1;
        }
    }
    __syncthreads();
    for (int i = t; i < NBKT; i += 256)
        gbase[i] = lhist[i] ? atomicAdd(&bcur[i], lhist[i]) : 0;
    __syncthreads();
#pragma unroll
    for (int it = 0; it < 16; ++it) {
        if (meta[it] >= 0) {
            int b = meta[it] & 2047;
            int r = meta[it] >> 11;
            pairs[(size_t)b * BCAP + gbase[b] + r] = wrd[it];
        }
    }
}

// ---------------------------------------------------------------------------
// Kernel 3: h = x @ W via split-bf16 MFMA (R5-passing version, unchanged).
__global__ __launch_bounds__(512) void mfma_gemm_kernel(
        const float* __restrict__ x, const short* __restrict__ wt_hi,
        const short* __restrict__ wt_lo, const float* __restrict__ att_src,
        const float* __restrict__ att_dst, unsigned short* __restrict__ h_bf,
        float* __restrict__ a_src, float* __restrict__ a_dst) {
    __shared__ short lw_hi[64 * LDK];   // 17 KB
    __shared__ short lw_lo[64 * LDK];   // 17 KB
    int t = threadIdx.x;
    int blk = blockIdx.x;

    for (int c = t; c < 1024; c += 512) {
        int n = c >> 4;
        int kk = (c & 15) * 8;
        *(bf16x8*)(lw_hi + n * LDK + kk) = *(const bf16x8*)(wt_hi + n * F_IN + kk);
        *(bf16x8*)(lw_lo + n * LDK + kk) = *(const bf16x8*)(wt_lo + n * F_IN + kk);
    }
    __syncthreads();

    int strip = blk * 8 + (t >> 6);
    int valid = strip < NSTRIP;
    int sclamp = valid ? strip : NSTRIP - 1;
    int lane = t & 63;
    int l15 = lane & 15;
    int q = lane >> 4;

    f32x4 acc[8];
#pragma unroll
    for (int nt = 0; nt < 8; ++nt) acc[nt] = (f32x4){0.f, 0.f, 0.f, 0.f};

    union BU { bf16x8 v; unsigned u[4]; };
    BU ah[4], al[4];
    const float* xp = x + (size_t)(sclamp * 16 + l15) * F_IN + q * 8;

#pragma unroll
    for (int ki = 0; ki < 4; ++ki) {
        float4 v0 = *(const float4*)(xp + ki * 32);
        float4 v1 = *(const float4*)(xp + ki * 32 + 4);
        float vv[8] = {v0.x, v0.y, v0.z, v0.w, v1.x, v1.y, v1.z, v1.w};
#pragma unroll
        for (int j = 0; j < 4; ++j) {
            float f0 = vv[2 * j], f1 = vv[2 * j + 1];
            unsigned hp = cvt_pk_bf16(f0, f1);
            ah[ki].u[j] = hp;
            float r0 = f0 - __uint_as_float(hp << 16);
            float r1 = f1 - __uint_as_float(hp & 0xFFFF0000u);
            al[ki].u[j] = cvt_pk_bf16(r0, r1);
        }
        int koff = ki * 32 + q * 8;
#pragma unroll
        for (int nt = 0; nt < 4; ++nt) {
            int lidx = (nt * 16 + l15) * LDK + koff;
            bf16x8 b_hi = *(const bf16x8*)(lw_hi + lidx);
            bf16x8 b_lo = *(const bf16x8*)(lw_lo + lidx);
            acc[nt] = __builtin_amdgcn_mfma_f32_16x16x32_bf16(ah[ki].v, b_hi, acc[nt], 0, 0, 0);
            acc[nt] = __builtin_amdgcn_mfma_f32_16x16x32_bf16(al[ki].v, b_hi, acc[nt], 0, 0, 0);
            acc[nt] = __builtin_amdgcn_mfma_f32_16x16x32_bf16(ah[ki].v, b_lo, acc[nt], 0, 0, 0);
        }
    }

    __syncthreads();
    for (int c = t; c < 1024; c += 512) {
        int n = c >> 4;
        int kk = (c & 15) * 8;
        *(bf16x8*)(lw_hi + n * LDK + kk) = *(const bf16x8*)(wt_hi + (64 + n) * F_IN + kk);
        *(bf16x8*)(lw_lo + n * LDK + kk) = *(const bf16x8*)(wt_lo + (64 + n) * F_IN + kk);
    }
    __syncthreads();

#pragma unroll
    for (int ki = 0; ki < 4; ++ki) {
        int koff = ki * 32 + q * 8;
#pragma unroll
        for (int nt = 0; nt < 4; ++nt) {
            int lidx = (nt * 16 + l15) * LDK + koff;
            bf16x8 b_hi = *(const bf16x8*)(lw_hi + lidx);
            bf16x8 b_lo = *(const bf16x8*)(lw_lo + lidx);
            acc[4 + nt] = __builtin_amdgcn_mfma_f32_16x16x32_bf16(ah[ki].v, b_hi, acc[4 + nt], 0, 0, 0);
            acc[4 + nt] = __builtin_amdgcn_mfma_f32_16x16x32_bf16(al[ki].v, b_hi, acc[4 + nt], 0, 0, 0);
            acc[4 + nt] = __builtin_amdgcn_mfma_f32_16x16x32_bf16(ah[ki].v, b_lo, acc[4 + nt], 0, 0, 0);
        }
    }

    if (!valid) return;

    int orow = strip * 16 + q * 4;
#pragma unroll
    for (int nt = 0; nt < 8; ++nt)
#pragma unroll
        for (int r = 0; r < 4; ++r)
            h_bf[(size_t)(orow + r) * HC + nt * 16 + l15] =
                (unsigned short)f2bf_rne(acc[nt][r]);

#pragma unroll
    for (int hd = 0; hd < 4; ++hd) {
        float as0 = att_src[hd * 32 + l15];
        float as1 = att_src[hd * 32 + 16 + l15];
        float ad0 = att_dst[hd * 32 + l15];
        float ad1 = att_dst[hd * 32 + 16 + l15];
#pragma unroll
        for (int r = 0; r < 4; ++r) {
            float ps = acc[2 * hd][r] * as0 + acc[2 * hd + 1][r] * as1;
            float pd = acc[2 * hd][r] * ad0 + acc[2 * hd + 1][r] * ad1;
#pragma unroll
            for (int off = 1; off < 16; off <<= 1) {
                ps += __shfl_xor(ps, off);
                pd += __shfl_xor(pd, off);
            }
            if (l15 == 0) {
                int row = orow + r;
                a_src[row * 4 + hd] = ps;
                a_dst[row * 4 + hd] = pd;
            }
        }
    }
}

// ---------------------------------------------------------------------------
// Kernel 4: bucket -> CSR + per-edge bf16 weights (R3-passing 64-node-bucket
// version, verbatim). 1563 blocks ~ 6/CU.
__global__ __launch_bounds__(256) void bucket_csr_kernel(
        const int* __restrict__ bcur, const unsigned* __restrict__ pairs,
        const float* __restrict__ a_src, const float* __restrict__ a_dst,
        int* __restrict__ deg, int* __restrict__ offsets,
        int* __restrict__ csr_src, unsigned* __restrict__ wal) {
    __shared__ unsigned lpairs[BCAP];   // 5 KB
    __shared__ int sd[256];
    __shared__ int cnt64[64];
    __shared__ int lcur[64];

    int b = blockIdx.x;
    int t = threadIdx.x;

    // bucket base = prefix sum of bcur[0..b)
    int partial = 0;
    for (int i = t; i < b; i += 256) partial += bcur[i];
    sd[t] = partial;
    __syncthreads();
    for (int off = 128; off > 0; off >>= 1) {
        if (t < off) sd[t] += sd[t + off];
        __syncthreads();
    }
    int bktbase = sd[0];
    __syncthreads();

    if (t < 64) cnt64[t] = 0;
    __syncthreads();

    int cnt = bcur[b];
    const unsigned* __restrict__ bp = pairs + (size_t)b * BCAP;
    for (int i = t; i < cnt; i += 256) {
        unsigned w = bp[i];
        lpairs[i] = w;
        atomicAdd(&cnt64[w >> 17], 1);
    }
    __syncthreads();

    // exclusive scan over the 64 per-node counts
    if (t < 64) sd[t] = cnt64[t];
    __syncthreads();
    for (int off = 1; off < 64; off <<= 1) {
        int u = 0;
        if (t < 64 && t >= off) u = sd[t - off];
        __syncthreads();
        if (t < 64) sd[t] += u;
        __syncthreads();
    }
    if (t < 64) {
        int v = cnt64[t];
        int myoff = bktbase + sd[t] - v;
        int node = (b << 6) + t;
        if (node < NN) {
            deg[node] = v;
            offsets[node] = myoff;
        }
        lcur[t] = myoff;
    }
    __syncthreads();

    for (int i = t; i < cnt; i += 256) {
        unsigned w = lpairs[i];
        int src = (int)(w & 0x1FFFFu);
        int dl = (int)(w >> 17);
        float4 as = ((const float4*)a_src)[src];
        float4 ad = ((const float4*)a_dst)[(b << 6) + dl];
        float e0 = as.x + ad.x; e0 = (e0 < 0.f) ? NEG_SLOPE * e0 : e0;
        float e1 = as.y + ad.y; e1 = (e1 < 0.f) ? NEG_SLOPE * e1 : e1;
        float e2 = as.z + ad.z; e2 = (e2 < 0.f) ? NEG_SLOPE * e2 : e2;
        float e3 = as.w + ad.w; e3 = (e3 < 0.f) ? NEG_SLOPE * e3 : e3;
        float w0 = __expf(e0), w1 = __expf(e1), w2 = __expf(e2), w3 = __expf(e3);
        int pos = atomicAdd(&lcur[dl], 1);
        csr_src[pos] = src;
        unsigned lo = (unsigned)(unsigned short)f2bf_rne(w0) |
                      ((unsigned)(unsigned short)f2bf_rne(w1) << 16);
        unsigned hi = (unsigned)(unsigned short)f2bf_rne(w2) |
                      ((unsigned)(unsigned short)f2bf_rne(w3) << 16);
        ((uint2*)wal)[pos] = make_uint2(lo, hi);
    }
}

// ---------------------------------------------------------------------------
// Kernel 5: per-node aggregation -- R5-passing version verbatim (wal-based
// bf16 weights, in-register wsum, pk math).
__global__ __launch_bounds__(256) void gat_aggr_kernel(
        const int* __restrict__ offsets, const int* __restrict__ deg,
        const int* __restrict__ csr_src, const unsigned* __restrict__ wal,
        const float* __restrict__ a_src, const float* __restrict__ a_dst,
        const unsigned* __restrict__ h2, const float* __restrict__ bias,
        float* __restrict__ out) {
    int wid = (blockIdx.x * 256 + threadIdx.x) >> 6;
    int dst = __builtin_amdgcn_readfirstlane(wid);
    if (dst >= NN) return;
    int lane = threadIdx.x & 63;
    int hd = lane >> 4;
    unsigned hsel2 = (unsigned)(hd & 2);
    unsigned shamt = (hd & 1) ? 0u : 16u;

    int start = offsets[dst];
    int n = deg[dst];

    f32x2 accx2 = {0.f, 0.f}, accy2 = {0.f, 0.f}, ws2 = {0.f, 0.f};

    int j = 0;
    for (; j + 7 < n; j += 8) {
        int base = start + j;
        int s0 = csr_src[base + 0];
        int s1 = csr_src[base + 1];
        int s2 = csr_src[base + 2];
        int s3 = csr_src[base + 3];
        int s4 = csr_src[base + 4];
        int s5 = csr_src[base + 5];
        int s6 = csr_src[base + 6];
        int s7 = csr_src[base + 7];
        uint2 wv0 = ((const uint2*)wal)[base + 0];
        uint2 wv1 = ((const uint2*)wal)[base + 1];
        uint2 wv2 = ((const uint2*)wal)[base + 2];
        uint2 wv3 = ((const uint2*)wal)[base + 3];
        uint2 wv4 = ((const uint2*)wal)[base + 4];
        uint2 wv5 = ((const uint2*)wal)[base + 5];
        uint2 wv6 = ((const uint2*)wal)[base + 6];
        uint2 wv7 = ((const uint2*)wal)[base + 7];
        unsigned u0 = h2[(size_t)s0 * 64 + lane];
        unsigned u1 = h2[(size_t)s1 * 64 + lane];
        unsigned u2 = h2[(size_t)s2 * 64 + lane];
        unsigned u3 = h2[(size_t)s3 * 64 + lane];
        unsigned u4 = h2[(size_t)s4 * 64 + lane];
        unsigned u5 = h2[(size_t)s5 * 64 + lane];
        unsigned u6 = h2[(size_t)s6 * 64 + lane];
        unsigned u7 = h2[(size_t)s7 * 64 + lane];
#define EDGEPAIR(ua, ub, wva, wvb)                                              \
        {                                                                       \
            unsigned wsa = hsel2 ? wva.y : wva.x;                               \
            unsigned wsb = hsel2 ? wvb.y : wvb.x;                               \
            f32x2 wp = mkpair(__uint_as_float((wsa << shamt) & 0xFFFF0000u),    \
                              __uint_as_float((wsb << shamt) & 0xFFFF0000u));   \
            f32x2 hx = mkpair(__uint_as_float(ua << 16),                        \
                              __uint_as_float(ub << 16));                       \
            f32x2 hy = mkpair(__uint_as_float(ua & 0xFFFF0000u),                \
                              __uint_as_float(ub & 0xFFFF0000u));               \
            pk_add(ws2, wp);                                                    \
            pk_fma(accx2, wp, hx);                                              \
            pk_fma(accy2, wp, hy);                                              \
        }
        EDGEPAIR(u0, u1, wv0, wv1)
        EDGEPAIR(u2, u3, wv2, wv3)
        EDGEPAIR(u4, u5, wv4, wv5)
        EDGEPAIR(u6, u7, wv6, wv7)
    }
    for (; j + 1 < n; j += 2) {
        int base = start + j;
        int s0 = csr_src[base + 0];
        int s1 = csr_src[base + 1];
        uint2 wv0 = ((const uint2*)wal)[base + 0];
        uint2 wv1 = ((const uint2*)wal)[base + 1];
        unsigned u0 = h2[(size_t)s0 * 64 + lane];
        unsigned u1 = h2[(size_t)s1 * 64 + lane];
        EDGEPAIR(u0, u1, wv0, wv1)
    }
#undef EDGEPAIR
    float accx = accx2.x + accx2.y;
    float accy = accy2.x + accy2.y;
    float wsum = ws2.x + ws2.y;
    if (j < n) {
        int base = start + j;
        int s0 = csr_src[base];
        uint2 wv0 = ((const uint2*)wal)[base];
        unsigned u0 = h2[(size_t)s0 * 64 + lane];
        unsigned ws0 = hsel2 ? wv0.y : wv0.x;
        float w0 = __uint_as_float((ws0 << shamt) & 0xFFFF0000u);
        wsum += w0;
        accx += w0 * __uint_as_float(u0 << 16);
        accy += w0 * __uint_as_float(u0 & 0xFFFF0000u);
    }

    // self-loop weight + softmax normalization
    float e = a_src[dst * 4 + hd] + a_dst[dst * 4 + hd];
    e = (e < 0.f) ? NEG_SLOPE * e : e;
    float sf = __expf(e);
    float inv = 1.f / (wsum + sf + 1e-16f);

    unsigned us = h2[(size_t)dst * 64 + lane];
    float2 b2 = ((const float2*)bias)[lane];
    float ox = tanhf((accx + sf * __uint_as_float(us << 16)) * inv + b2.x);
    float oy = tanhf((accy + sf * __uint_as_float(us & 0xFFFF0000u)) * inv + b2.y);
    ((float2*)out)[(size_t)dst * 64 + lane] = make_float2(ox, oy);
}

// ---------------------------------------------------------------------------
extern "C" void kernel_launch(void* const* d_in, const int* in_sizes, int n_in,
                              void* d_out, int out_size, void* d_ws, size_t ws_size,
                              hipStream_t stream) {
    const float* x       = (const float*)d_in[0];
    const int*   ei      = (const int*)  d_in[1];
    const float* W       = (const float*)d_in[2];
    const float* att_src = (const float*)d_in[3];
    const float* att_dst = (const float*)d_in[4];
    const float* bias    = (const float*)d_in[5];
    float* out = (float*)d_out;

    unsigned short* h_bf = (unsigned short*)d_ws;            // NN*128 bf16 (25.6 MB)
    float* a_src = (float*)(h_bf + (size_t)NN * HC);         // NN*4
    float* a_dst = a_src + (size_t)NN * HEADS;               // NN*4
    short* wt_hi = (short*)(a_dst + (size_t)NN * HEADS);     // 16384
    short* wt_lo = wt_hi + F_IN * HC;                        // 16384
    int* flag    = (int*)(wt_lo + F_IN * HC);
    int* bcur    = flag + 4;                 // NBKT
    int* deg     = bcur + NBKT + 1;          // NN
    int* offsets = deg + NN;                 // NN
    int* csr_src = offsets + NN;             // NE (6.4 MB)
    unsigned* wal = (unsigned*)(csr_src + NE);               // NE*2 (12.8 MB)
    unsigned* pairs = (unsigned*)(wal + (size_t)NE * 2);     // NBKT*BCAP (8 MB)

    hipMemsetAsync(bcur, 0, NBKT * sizeof(int), stream);

    hipLaunchKernelGGL(prep_kernel, dim3(64), dim3(256), 0, stream,
                       W, wt_hi, wt_lo, ei, flag);

    hipLaunchKernelGGL(bucket_scatter_kernel, dim3((NE + 4095) / 4096), dim3(256), 0, stream,
                       ei, flag, bcur, pairs);

    hipLaunchKernelGGL(mfma_gemm_kernel, dim3(782), dim3(512), 0, stream,
                       x, wt_hi, wt_lo, att_src, att_dst, h_bf, a_src, a_dst);

    hipLaunchKernelGGL(bucket_csr_kernel, dim3(NBKT), dim3(256), 0, stream,
                       bcur, pairs, a_src, a_dst, deg, offsets, csr_src, wal);

    hipLaunchKernelGGL(gat_aggr_kernel, dim3(NN * 64 / 256), dim3(256), 0, stream,
                       offsets, deg, csr_src, wal, a_src, a_dst,
                       (const unsigned*)h_bf, bias, out);
}

// Round 8
// 253.145 us; speedup vs baseline: 1.8138x; 1.0178x over previous
//
#include <hip/hip_runtime.h>
#include <math.h>

#define NN 100000
#define NE 1600000
#define F_IN 128
#define HEADS 4
#define HC 128
#define NEG_SLOPE 0.2f
#define NBKT 391    // buckets of 256 dst nodes: (NN+255)/256  (scatter-coalescing optimum)
#define BCAP 5120   // bucket capacity (mean 4096, sd 64 -> +16 sigma; R0-proven)
#define LDK 136     // padded LDS row (bf16): 128 + 8 -> 2-way bank alias (free)
#define NSTRIP 6250 // NN/16

typedef __attribute__((ext_vector_type(8))) short bf16x8;
typedef __attribute__((ext_vector_type(4))) float f32x4;
typedef __attribute__((ext_vector_type(2))) float f32x2;

static __device__ __forceinline__ short f2bf_rne(float f) {
    unsigned u = __float_as_uint(f);
    unsigned r = (u + 0x7FFFu + ((u >> 16) & 1u)) >> 16;
    return (short)r;
}
static __device__ __forceinline__ float bf2f(short s) {
    return __uint_as_float(((unsigned)(unsigned short)s) << 16);
}
// 2x f32 -> packed bf16 (RNE), one instruction
static __device__ __forceinline__ unsigned cvt_pk_bf16(float a, float b) {
    unsigned r;
    asm("v_cvt_pk_bf16_f32 %0, %1, %2" : "=v"(r) : "v"(a), "v"(b));
    return r;
}

// packed fp32 math (CDNA: full-rate V_PK_*_F32)
static __device__ __forceinline__ void pk_fma(f32x2& d, f32x2 a, f32x2 b) {
    asm("v_pk_fma_f32 %0, %1, %2, %0 op_sel:[0,0,0] op_sel_hi:[1,1,1]"
        : "+v"(d) : "v"(a), "v"(b));
}
static __device__ __forceinline__ void pk_add(f32x2& d, f32x2 a) {
    asm("v_pk_add_f32 %0, %1, %0 op_sel:[0,0] op_sel_hi:[1,1]"
        : "+v"(d) : "v"(a));
}
static __device__ __forceinline__ f32x2 mkpair(float a, float b) {
    f32x2 r; r.x = a; r.y = b; return r;
}

// ---------------------------------------------------------------------------
// Kernel 1: W prep (transpose + bf16 hi/lo split) + int64/int32 detect (blk 0).
__global__ __launch_bounds__(256) void prep_kernel(
        const float* __restrict__ W, short* __restrict__ wt_hi, short* __restrict__ wt_lo,
        const int* __restrict__ ei, int* __restrict__ flag) {
    if (blockIdx.x == 0 && threadIdx.x < 64) {
        int l = threadIdx.x;
        int v = ei[2 * l + 1];
        for (int off = 1; off < 64; off <<= 1) v |= __shfl_xor(v, off);
        if (l == 0) *flag = (v == 0) ? 1 : 0;   // 1 => int64 layout
    }
    int i = blockIdx.x * 256 + threadIdx.x;
    if (i >= F_IN * HC) return;
    int k = i >> 7, n = i & 127;
    float f = W[k * HC + n];
    short hb = f2bf_rne(f);
    wt_hi[n * F_IN + k] = hb;
    wt_lo[n * F_IN + k] = f2bf_rne(f - bf2f(hb));
}

// ---------------------------------------------------------------------------
// Kernel 2: bucketed multisplit, R0-proven 256-node-bucket layout. 4096 edges
// over 391 buckets -> ~10.5 consecutive slots per (block,bucket): pairs writes
// coalesce into ~10-element line runs (the 64-node variant degraded to ~2.6).
__global__ __launch_bounds__(256) void bucket_scatter_kernel(
        const int* __restrict__ ei, const int* __restrict__ flag,
        int* __restrict__ bcur, unsigned* __restrict__ pairs) {
    __shared__ int lhist[NBKT];
    __shared__ int gbase[NBKT];
    int t = threadIdx.x;
    for (int i = t; i < NBKT; i += 256) lhist[i] = 0;
    __syncthreads();
    int is64 = *flag;
    int base = blockIdx.x * 4096;

    unsigned wrd[16];
    int meta[16];
#pragma unroll
    for (int it = 0; it < 16; ++it) {
        int e = base + it * 256 + t;
        if (e < NE) {
            int src = is64 ? ei[2 * e] : ei[e];
            int dst = is64 ? ei[2 * NE + 2 * e] : ei[NE + e];
            int b = dst >> 8;
            int r = atomicAdd(&lhist[b], 1);
            wrd[it] = (unsigned)src | ((unsigned)(dst & 255) << 17);
            meta[it] = b | (r << 9);
        } else {
            meta[it] = -1;
        }
    }
    __syncthreads();
    for (int i = t; i < NBKT; i += 256)
        gbase[i] = lhist[i] ? atomicAdd(&bcur[i], lhist[i]) : 0;
    __syncthreads();
#pragma unroll
    for (int it = 0; it < 16; ++it) {
        if (meta[it] >= 0) {
            int b = meta[it] & 511;
            int r = meta[it] >> 9;
            pairs[(size_t)b * BCAP + gbase[b] + r] = wrd[it];
        }
    }
}

// ---------------------------------------------------------------------------
// Kernel 3: h = x @ W via split-bf16 MFMA (R7-passing version, unchanged).
__global__ __launch_bounds__(512) void mfma_gemm_kernel(
        const float* __restrict__ x, const short* __restrict__ wt_hi,
        const short* __restrict__ wt_lo, const float* __restrict__ att_src,
        const float* __restrict__ att_dst, unsigned short* __restrict__ h_bf,
        float* __restrict__ a_src, float* __restrict__ a_dst) {
    __shared__ short lw_hi[64 * LDK];   // 17 KB
    __shared__ short lw_lo[64 * LDK];   // 17 KB
    int t = threadIdx.x;
    int blk = blockIdx.x;

    for (int c = t; c < 1024; c += 512) {
        int n = c >> 4;
        int kk = (c & 15) * 8;
        *(bf16x8*)(lw_hi + n * LDK + kk) = *(const bf16x8*)(wt_hi + n * F_IN + kk);
        *(bf16x8*)(lw_lo + n * LDK + kk) = *(const bf16x8*)(wt_lo + n * F_IN + kk);
    }
    __syncthreads();

    int strip = blk * 8 + (t >> 6);
    int valid = strip < NSTRIP;
    int sclamp = valid ? strip : NSTRIP - 1;
    int lane = t & 63;
    int l15 = lane & 15;
    int q = lane >> 4;

    f32x4 acc[8];
#pragma unroll
    for (int nt = 0; nt < 8; ++nt) acc[nt] = (f32x4){0.f, 0.f, 0.f, 0.f};

    union BU { bf16x8 v; unsigned u[4]; };
    BU ah[4], al[4];
    const float* xp = x + (size_t)(sclamp * 16 + l15) * F_IN + q * 8;

#pragma unroll
    for (int ki = 0; ki < 4; ++ki) {
        float4 v0 = *(const float4*)(xp + ki * 32);
        float4 v1 = *(const float4*)(xp + ki * 32 + 4);
        float vv[8] = {v0.x, v0.y, v0.z, v0.w, v1.x, v1.y, v1.z, v1.w};
#pragma unroll
        for (int j = 0; j < 4; ++j) {
            float f0 = vv[2 * j], f1 = vv[2 * j + 1];
            unsigned hp = cvt_pk_bf16(f0, f1);
            ah[ki].u[j] = hp;
            float r0 = f0 - __uint_as_float(hp << 16);
            float r1 = f1 - __uint_as_float(hp & 0xFFFF0000u);
            al[ki].u[j] = cvt_pk_bf16(r0, r1);
        }
        int koff = ki * 32 + q * 8;
#pragma unroll
        for (int nt = 0; nt < 4; ++nt) {
            int lidx = (nt * 16 + l15) * LDK + koff;
            bf16x8 b_hi = *(const bf16x8*)(lw_hi + lidx);
            bf16x8 b_lo = *(const bf16x8*)(lw_lo + lidx);
            acc[nt] = __builtin_amdgcn_mfma_f32_16x16x32_bf16(ah[ki].v, b_hi, acc[nt], 0, 0, 0);
            acc[nt] = __builtin_amdgcn_mfma_f32_16x16x32_bf16(al[ki].v, b_hi, acc[nt], 0, 0, 0);
            acc[nt] = __builtin_amdgcn_mfma_f32_16x16x32_bf16(ah[ki].v, b_lo, acc[nt], 0, 0, 0);
        }
    }

    __syncthreads();
    for (int c = t; c < 1024; c += 512) {
        int n = c >> 4;
        int kk = (c & 15) * 8;
        *(bf16x8*)(lw_hi + n * LDK + kk) = *(const bf16x8*)(wt_hi + (64 + n) * F_IN + kk);
        *(bf16x8*)(lw_lo + n * LDK + kk) = *(const bf16x8*)(wt_lo + (64 + n) * F_IN + kk);
    }
    __syncthreads();

#pragma unroll
    for (int ki = 0; ki < 4; ++ki) {
        int koff = ki * 32 + q * 8;
#pragma unroll
        for (int nt = 0; nt < 4; ++nt) {
            int lidx = (nt * 16 + l15) * LDK + koff;
            bf16x8 b_hi = *(const bf16x8*)(lw_hi + lidx);
            bf16x8 b_lo = *(const bf16x8*)(lw_lo + lidx);
            acc[4 + nt] = __builtin_amdgcn_mfma_f32_16x16x32_bf16(ah[ki].v, b_hi, acc[4 + nt], 0, 0, 0);
            acc[4 + nt] = __builtin_amdgcn_mfma_f32_16x16x32_bf16(al[ki].v, b_hi, acc[4 + nt], 0, 0, 0);
            acc[4 + nt] = __builtin_amdgcn_mfma_f32_16x16x32_bf16(ah[ki].v, b_lo, acc[4 + nt], 0, 0, 0);
        }
    }

    if (!valid) return;

    int orow = strip * 16 + q * 4;
#pragma unroll
    for (int nt = 0; nt < 8; ++nt)
#pragma unroll
        for (int r = 0; r < 4; ++r)
            h_bf[(size_t)(orow + r) * HC + nt * 16 + l15] =
                (unsigned short)f2bf_rne(acc[nt][r]);

#pragma unroll
    for (int hd = 0; hd < 4; ++hd) {
        float as0 = att_src[hd * 32 + l15];
        float as1 = att_src[hd * 32 + 16 + l15];
        float ad0 = att_dst[hd * 32 + l15];
        float ad1 = att_dst[hd * 32 + 16 + l15];
#pragma unroll
        for (int r = 0; r < 4; ++r) {
            float ps = acc[2 * hd][r] * as0 + acc[2 * hd + 1][r] * as1;
            float pd = acc[2 * hd][r] * ad0 + acc[2 * hd + 1][r] * ad1;
#pragma unroll
            for (int off = 1; off < 16; off <<= 1) {
                ps += __shfl_xor(ps, off);
                pd += __shfl_xor(pd, off);
            }
            if (l15 == 0) {
                int row = orow + r;
                a_src[row * 4 + hd] = ps;
                a_dst[row * 4 + hd] = pd;
            }
        }
    }
}

// ---------------------------------------------------------------------------
// Kernel 4: bucket -> CSR + per-edge bf16 weights. 256-node buckets, but
// 1024-thread blocks: grid stays 391 (1.5 blocks/CU) while waves/CU go
// 6 -> 24 -- the occupancy fix WITHOUT shrinking buckets (which would
// de-coalesce the scatter's writes). All scans 256-wide, guarded; every
// thread reaches every barrier.
__global__ __launch_bounds__(1024) void bucket_csr_kernel(
        const int* __restrict__ bcur, const unsigned* __restrict__ pairs,
        const float* __restrict__ a_src, const float* __restrict__ a_dst,
        int* __restrict__ deg, int* __restrict__ offsets,
        int* __restrict__ csr_src, unsigned* __restrict__ wal) {
    __shared__ unsigned lpairs[BCAP];   // 20 KB
    __shared__ int sd[1024];            // 4 KB
    __shared__ int cnt256[256];
    __shared__ int lcur[256];

    int b = blockIdx.x;
    int t = threadIdx.x;

    // bucket base = prefix sum of bcur[0..b)
    int partial = 0;
    for (int i = t; i < b; i += 1024) partial += bcur[i];
    sd[t] = partial;
    __syncthreads();
    for (int off = 512; off > 0; off >>= 1) {
        if (t < off) sd[t] += sd[t + off];
        __syncthreads();
    }
    int bktbase = sd[0];
    __syncthreads();

    if (t < 256) cnt256[t] = 0;
    __syncthreads();

    int cnt = bcur[b];
    const unsigned* __restrict__ bp = pairs + (size_t)b * BCAP;
    for (int i = t; i < cnt; i += 1024) {
        unsigned w = bp[i];
        lpairs[i] = w;
        atomicAdd(&cnt256[w >> 17], 1);
    }
    __syncthreads();

    // exclusive scan over the 256 per-node counts (first 256 threads; guarded)
    if (t < 256) sd[t] = cnt256[t];
    __syncthreads();
    for (int off = 1; off < 256; off <<= 1) {
        int u = 0;
        if (t < 256 && t >= off) u = sd[t - off];
        __syncthreads();
        if (t < 256) sd[t] += u;
        __syncthreads();
    }
    if (t < 256) {
        int v = cnt256[t];
        int myoff = bktbase + sd[t] - v;
        int node = (b << 8) + t;
        if (node < NN) {
            deg[node] = v;
            offsets[node] = myoff;
        }
        lcur[t] = myoff;
    }
    __syncthreads();

    for (int i = t; i < cnt; i += 1024) {
        unsigned w = lpairs[i];
        int src = (int)(w & 0x1FFFFu);
        int dl = (int)(w >> 17);
        float4 as = ((const float4*)a_src)[src];
        float4 ad = ((const float4*)a_dst)[(b << 8) + dl];
        float e0 = as.x + ad.x; e0 = (e0 < 0.f) ? NEG_SLOPE * e0 : e0;
        float e1 = as.y + ad.y; e1 = (e1 < 0.f) ? NEG_SLOPE * e1 : e1;
        float e2 = as.z + ad.z; e2 = (e2 < 0.f) ? NEG_SLOPE * e2 : e2;
        float e3 = as.w + ad.w; e3 = (e3 < 0.f) ? NEG_SLOPE * e3 : e3;
        float w0 = __expf(e0), w1 = __expf(e1), w2 = __expf(e2), w3 = __expf(e3);
        int pos = atomicAdd(&lcur[dl], 1);
        csr_src[pos] = src;
        unsigned lo = (unsigned)(unsigned short)f2bf_rne(w0) |
                      ((unsigned)(unsigned short)f2bf_rne(w1) << 16);
        unsigned hi = (unsigned)(unsigned short)f2bf_rne(w2) |
                      ((unsigned)(unsigned short)f2bf_rne(w3) << 16);
        ((uint2*)wal)[pos] = make_uint2(lo, hi);
    }
}

// ---------------------------------------------------------------------------
// Kernel 5: per-node aggregation -- R7-passing version verbatim (wal-based
// bf16 weights, in-register wsum, pk math).
__global__ __launch_bounds__(256) void gat_aggr_kernel(
        const int* __restrict__ offsets, const int* __restrict__ deg,
        const int* __restrict__ csr_src, const unsigned* __restrict__ wal,
        const float* __restrict__ a_src, const float* __restrict__ a_dst,
        const unsigned* __restrict__ h2, const float* __restrict__ bias,
        float* __restrict__ out) {
    int wid = (blockIdx.x * 256 + threadIdx.x) >> 6;
    int dst = __builtin_amdgcn_readfirstlane(wid);
    if (dst >= NN) return;
    int lane = threadIdx.x & 63;
    int hd = lane >> 4;
    unsigned hsel2 = (unsigned)(hd & 2);
    unsigned shamt = (hd & 1) ? 0u : 16u;

    int start = offsets[dst];
    int n = deg[dst];

    f32x2 accx2 = {0.f, 0.f}, accy2 = {0.f, 0.f}, ws2 = {0.f, 0.f};

    int j = 0;
    for (; j + 7 < n; j += 8) {
        int base = start + j;
        int s0 = csr_src[base + 0];
        int s1 = csr_src[base + 1];
        int s2 = csr_src[base + 2];
        int s3 = csr_src[base + 3];
        int s4 = csr_src[base + 4];
        int s5 = csr_src[base + 5];
        int s6 = csr_src[base + 6];
        int s7 = csr_src[base + 7];
        uint2 wv0 = ((const uint2*)wal)[base + 0];
        uint2 wv1 = ((const uint2*)wal)[base + 1];
        uint2 wv2 = ((const uint2*)wal)[base + 2];
        uint2 wv3 = ((const uint2*)wal)[base + 3];
        uint2 wv4 = ((const uint2*)wal)[base + 4];
        uint2 wv5 = ((const uint2*)wal)[base + 5];
        uint2 wv6 = ((const uint2*)wal)[base + 6];
        uint2 wv7 = ((const uint2*)wal)[base + 7];
        unsigned u0 = h2[(size_t)s0 * 64 + lane];
        unsigned u1 = h2[(size_t)s1 * 64 + lane];
        unsigned u2 = h2[(size_t)s2 * 64 + lane];
        unsigned u3 = h2[(size_t)s3 * 64 + lane];
        unsigned u4 = h2[(size_t)s4 * 64 + lane];
        unsigned u5 = h2[(size_t)s5 * 64 + lane];
        unsigned u6 = h2[(size_t)s6 * 64 + lane];
        unsigned u7 = h2[(size_t)s7 * 64 + lane];
#define EDGEPAIR(ua, ub, wva, wvb)                                              \
        {                                                                       \
            unsigned wsa = hsel2 ? wva.y : wva.x;                               \
            unsigned wsb = hsel2 ? wvb.y : wvb.x;                               \
            f32x2 wp = mkpair(__uint_as_float((wsa << shamt) & 0xFFFF0000u),    \
                              __uint_as_float((wsb << shamt) & 0xFFFF0000u));   \
            f32x2 hx = mkpair(__uint_as_float(ua << 16),                        \
                              __uint_as_float(ub << 16));                       \
            f32x2 hy = mkpair(__uint_as_float(ua & 0xFFFF0000u),                \
                              __uint_as_float(ub & 0xFFFF0000u));               \
            pk_add(ws2, wp);                                                    \
            pk_fma(accx2, wp, hx);                                              \
            pk_fma(accy2, wp, hy);                                              \
        }
        EDGEPAIR(u0, u1, wv0, wv1)
        EDGEPAIR(u2, u3, wv2, wv3)
        EDGEPAIR(u4, u5, wv4, wv5)
        EDGEPAIR(u6, u7, wv6, wv7)
    }
    for (; j + 1 < n; j += 2) {
        int base = start + j;
        int s0 = csr_src[base + 0];
        int s1 = csr_src[base + 1];
        uint2 wv0 = ((const uint2*)wal)[base + 0];
        uint2 wv1 = ((const uint2*)wal)[base + 1];
        unsigned u0 = h2[(size_t)s0 * 64 + lane];
        unsigned u1 = h2[(size_t)s1 * 64 + lane];
        EDGEPAIR(u0, u1, wv0, wv1)
    }
#undef EDGEPAIR
    float accx = accx2.x + accx2.y;
    float accy = accy2.x + accy2.y;
    float wsum = ws2.x + ws2.y;
    if (j < n) {
        int base = start + j;
        int s0 = csr_src[base];
        uint2 wv0 = ((const uint2*)wal)[base];
        unsigned u0 = h2[(size_t)s0 * 64 + lane];
        unsigned ws0 = hsel2 ? wv0.y : wv0.x;
        float w0 = __uint_as_float((ws0 << shamt) & 0xFFFF0000u);
        wsum += w0;
        accx += w0 * __uint_as_float(u0 << 16);
        accy += w0 * __uint_as_float(u0 & 0xFFFF0000u);
    }

    // self-loop weight + softmax normalization
    float e = a_src[dst * 4 + hd] + a_dst[dst * 4 + hd];
    e = (e < 0.f) ? NEG_SLOPE * e : e;
    float sf = __expf(e);
    float inv = 1.f / (wsum + sf + 1e-16f);

    unsigned us = h2[(size_t)dst * 64 + lane];
    float2 b2 = ((const float2*)bias)[lane];
    float ox = tanhf((accx + sf * __uint_as_float(us << 16)) * inv + b2.x);
    float oy = tanhf((accy + sf * __uint_as_float(us & 0xFFFF0000u)) * inv + b2.y);
    ((float2*)out)[(size_t)dst * 64 + lane] = make_float2(ox, oy);
}

// ---------------------------------------------------------------------------
extern "C" void kernel_launch(void* const* d_in, const int* in_sizes, int n_in,
                              void* d_out, int out_size, void* d_ws, size_t ws_size,
                              hipStream_t stream) {
    const float* x       = (const float*)d_in[0];
    const int*   ei      = (const int*)  d_in[1];
    const float* W       = (const float*)d_in[2];
    const float* att_src = (const float*)d_in[3];
    const float* att_dst = (const float*)d_in[4];
    const float* bias    = (const float*)d_in[5];
    float* out = (float*)d_out;

    unsigned short* h_bf = (unsigned short*)d_ws;            // NN*128 bf16 (25.6 MB)
    float* a_src = (float*)(h_bf + (size_t)NN * HC);         // NN*4
    float* a_dst = a_src + (size_t)NN * HEADS;               // NN*4
    short* wt_hi = (short*)(a_dst + (size_t)NN * HEADS);     // 16384
    short* wt_lo = wt_hi + F_IN * HC;                        // 16384
    int* flag    = (int*)(wt_lo + F_IN * HC);
    int* bcur    = flag + 4;                 // NBKT
    int* deg     = bcur + NBKT + 1;          // NN
    int* offsets = deg + NN;                 // NN
    int* csr_src = offsets + NN;             // NE (6.4 MB)
    unsigned* wal = (unsigned*)(csr_src + NE);               // NE*2 (12.8 MB)
    unsigned* pairs = (unsigned*)(wal + (size_t)NE * 2);     // NBKT*BCAP (8 MB)

    hipMemsetAsync(bcur, 0, NBKT * sizeof(int), stream);

    hipLaunchKernelGGL(prep_kernel, dim3(64), dim3(256), 0, stream,
                       W, wt_hi, wt_lo, ei, flag);

    hipLaunchKernelGGL(bucket_scatter_kernel, dim3((NE + 4095) / 4096), dim3(256), 0, stream,
                       ei, flag, bcur, pairs);

    hipLaunchKernelGGL(mfma_gemm_kernel, dim3(782), dim3(512), 0, stream,
                       x, wt_hi, wt_lo, att_src, att_dst, h_bf, a_src, a_dst);

    hipLaunchKernelGGL(bucket_csr_kernel, dim3(NBKT), dim3(1024), 0, stream,
                       bcur, pairs, a_src, a_dst, deg, offsets, csr_src, wal);

    hipLaunchKernelGGL(gat_aggr_kernel, dim3(NN * 64 / 256), dim3(256), 0, stream,
                       offsets, deg, csr_src, wal, a_src, a_dst,
                       (const unsigned*)h_bf, bias, out);
}